// Round 7
// baseline (2869.671 us; speedup 1.0000x reference)
//
#include <hip/hip_runtime.h>
#include <stdint.h>

typedef unsigned short ushort_t;
typedef unsigned long long ull_t;
typedef __attribute__((ext_vector_type(8))) short short8;      // 8 bf16 (4 VGPRs)
typedef __attribute__((ext_vector_type(2))) unsigned long long ull2;
typedef __attribute__((ext_vector_type(4))) float f32x4;       // MFMA 16x16 acc
typedef __attribute__((ext_vector_type(4))) float float4v;
typedef __attribute__((ext_vector_type(4))) unsigned short ushort4v;
typedef __attribute__((ext_vector_type(4))) unsigned int uint4v;

#define NB 64
#define NT 512
#define ND 1024
#define NHH 1024
#define NG 4096

__device__ __forceinline__ ushort_t f2bf(float x) {
    uint32_t u = __builtin_bit_cast(uint32_t, x);
    u += 0x7fffu + ((u >> 16) & 1u);   // RTNE
    return (ushort_t)(u >> 16);
}
__device__ __forceinline__ float bf2f(ushort_t b) {
    uint32_t u = ((uint32_t)b) << 16;
    return __builtin_bit_cast(float, u);
}
__device__ __forceinline__ float fsigmoid(float x) { return 1.f / (1.f + __expf(-x)); }
__device__ __forceinline__ float ftanh(float x) {
    float ax = __builtin_fabsf(x);
    float e = __expf(-2.f * ax);
    float r = (1.f - e) / (1.f + e);
    return x < 0.f ? -r : r;
}
__device__ __forceinline__ void xg_store(float* p, float v) { *p = v; }
__device__ __forceinline__ void xg_store(ushort_t* p, float v) { *p = f2bf(v); }
__device__ __forceinline__ float4v xg_load4(const float4v* p) { return *p; }
__device__ __forceinline__ float4v xg_load4(const ushort4v* p) {
    ushort4v u = *p;
    float4v r = { bf2f(u[0]), bf2f(u[1]), bf2f(u[2]), bf2f(u[3]) };
    return r;
}
// async global->LDS 16B copy: LDS dest is wave-uniform base + lane*16
__device__ __forceinline__ void async_cp16(const ushort_t* g, ushort_t* s) {
    __builtin_amdgcn_global_load_lds(
        (const __attribute__((address_space(1))) uint32_t*)g,
        (__attribute__((address_space(3))) uint32_t*)s, 16, 0, 0);
}

// ---------------- prep: fp32->bf16 conversions (W_ih row-PERMUTED: r' = j*4+gate
// so k_gemm's natural output layout is gate-interleaved float4), zero h buffers,
// zero barrier counters.
__global__ __launch_bounds__(256) void k_prep(
    const float* __restrict__ feat, const float* __restrict__ wih,
    const float* __restrict__ whh,
    ushort_t* __restrict__ featb, ushort_t* __restrict__ wihb,
    ushort_t* __restrict__ whhb, ushort_t* __restrict__ hbuf,
    int* __restrict__ cnt)
{
    const size_t NF = (size_t)NB * NT * ND / 4;   // 8388608 float4 chunks
    const size_t NW = (size_t)NG * ND / 4;        // 1048576
    const size_t NHB = (size_t)2 * 65536 * 2 / 16; // 16384 16B chunks
    size_t total = NF + 2 * NW + NHB;
    size_t stride = (size_t)gridDim.x * blockDim.x;
    for (size_t i = (size_t)blockIdx.x * blockDim.x + threadIdx.x; i < total; i += stride) {
        if (i < NF) {
            float4v v = ((const float4v*)feat)[i];
            ushort4v o = { f2bf(v[0]), f2bf(v[1]), f2bf(v[2]), f2bf(v[3]) };
            ((ushort4v*)featb)[i] = o;
        } else if (i < NF + NW) {
            size_t j = i - NF;                      // chunk over [4096 rows][256 f4]
            size_t row = j >> 8, kc = j & 255;
            size_t rowp = ((row & 1023) << 2) | (row >> 10);   // j*4 + gate
            float4v v = ((const float4v*)wih)[j];
            ushort4v o = { f2bf(v[0]), f2bf(v[1]), f2bf(v[2]), f2bf(v[3]) };
            ((ushort4v*)wihb)[rowp * 256 + kc] = o;
        } else if (i < NF + 2 * NW) {
            size_t j = i - NF - NW;
            float4v v = ((const float4v*)whh)[j];
            ushort4v o = { f2bf(v[0]), f2bf(v[1]), f2bf(v[2]), f2bf(v[3]) };
            ((ushort4v*)whhb)[j] = o;
        } else {
            size_t j = i - NF - 2 * NW;
            uint4v z = { 0u, 0u, 0u, 0u };
            ((uint4v*)hbuf)[j] = z;
        }
    }
    // Zero the FULL 4096-int barrier region (16 blocks x 256 threads).
    if (blockIdx.x < 16) cnt[blockIdx.x * 256 + threadIdx.x] = 0;
}

// ---------------- x_gates GEMM: xg[t][b][rp] = feat[b,t,:] . Wih'[rp,:] + bias[rp]
// rp = j*4+gate (permuted). 128x128 tile, BK=64, 256 threads.
// m97-style: global_load_lds width-16 staging, 2-barrier K-loop, XOR bank swizzle.
template <typename XGT>
__global__ __launch_bounds__(256) void k_gemm(
    const ushort_t* __restrict__ Ab,   // feature bf16 [32768][1024]
    const ushort_t* __restrict__ Bb,   // W_ih' bf16 [4096][1024] (row-permuted)
    const float* __restrict__ bih, const float* __restrict__ bhh,
    const int* __restrict__ slenp, XGT* __restrict__ xg)
{
    int bid = blockIdx.x;                  // 8192 tiles
    int panel = bid >> 8;                  // 32 panels of (8 mt x 32 nt) for L2 reuse
    int qq = bid & 255;
    int mt = (panel << 3) | (qq & 7);
    int nt = qq >> 3;
    int m0 = mt << 7, n0 = nt << 7;
    int b = m0 >> 9;                       // 128-row tile lies within one batch
    int t0 = m0 & 511;
    int sl = slenp[b];
    if (t0 >= sl) return;                  // whole tile masked: xg never read there

    __shared__ short8 ldsA8[1024];         // 128 rows x 8 chunks (16 KB), swizzled
    __shared__ short8 ldsB8[1024];
    ushort_t* ldsA = (ushort_t*)ldsA8;
    ushort_t* ldsB = (ushort_t*)ldsB8;
    const ushort_t* gA = Ab + (size_t)m0 * 1024;
    const ushort_t* gB = Bb + (size_t)n0 * 1024;

    int tid = threadIdx.x;
    int wave = tid >> 6, lane = tid & 63;
    int wm = (wave >> 1) << 6;
    int wn = (wave & 1) << 6;
    int fl = lane & 15, fq = lane >> 4;

    f32x4 acc[4][4];
#pragma unroll
    for (int i = 0; i < 4; i++)
#pragma unroll
        for (int j = 0; j < 4; j++) { f32x4 z = {0.f, 0.f, 0.f, 0.f}; acc[i][j] = z; }

    // per-thread staging coords: slot s = u*256 + tid; row = s>>3, kb = (s&7)^(row&7)
    int srow_[4], skb_[4];
#pragma unroll
    for (int u = 0; u < 4; u++) {
        int s = u * 256 + tid;
        srow_[u] = s >> 3;
        skb_[u] = (s & 7) ^ (srow_[u] & 7);
    }

    for (int k0 = 0; k0 < 1024; k0 += 64) {
        if (k0) __syncthreads();           // protect LDS from previous iter's reads
#pragma unroll
        for (int u = 0; u < 4; u++) {
            ushort_t* sa = ldsA + (size_t)(u * 256 + wave * 64) * 8;
            ushort_t* sb = ldsB + (size_t)(u * 256 + wave * 64) * 8;
            async_cp16(gA + (size_t)srow_[u] * 1024 + k0 + skb_[u] * 8, sa);
            async_cp16(gB + (size_t)srow_[u] * 1024 + k0 + skb_[u] * 8, sb);
        }
        __syncthreads();                   // drains vmcnt: LDS tiles ready
#pragma unroll
        for (int ks = 0; ks < 2; ks++) {
            int kc = ks * 4 + fq;          // 16B chunk within BK=64
            short8 af[4], bf[4];
#pragma unroll
            for (int i = 0; i < 4; i++) {
                int ra = wm + i * 16 + fl;
                int rb = wn + i * 16 + fl;
                af[i] = ldsA8[ra * 8 + (kc ^ (ra & 7))];
                bf[i] = ldsB8[rb * 8 + (kc ^ (rb & 7))];
            }
#pragma unroll
            for (int i = 0; i < 4; i++)
#pragma unroll
                for (int j = 0; j < 4; j++)
                    acc[i][j] = __builtin_amdgcn_mfma_f32_16x16x32_bf16(af[i], bf[j], acc[i][j], 0, 0, 0);
        }
    }
    // epilogue: C layout col=lane&15, row=quad*4+reg. Columns are permuted rows rp.
#pragma unroll
    for (int j = 0; j < 4; j++) {
        int rp = n0 + wn + j * 16 + fl;              // permuted row index
        int bi = ((rp & 3) << 10) | (rp >> 2);       // gate*1024 + j
        float bv = bih[bi] + bhh[bi];
#pragma unroll
        for (int i = 0; i < 4; i++) {
#pragma unroll
            for (int r = 0; r < 4; r++) {
                int m = wm + i * 16 + fq * 4 + r;
                int t = t0 + m;
                if (t < sl)
                    xg_store(&xg[((size_t)t * 64 + b) * 4096 + rp], acc[i][j][r] + bv);
            }
        }
    }
}

// ---------------- persistent recurrence kernel: 128 WGs x 512 thr
// WG = (mb: 16-batch block) x (jw: 32 h-columns); 32 WGs per mb cover the FULL
// 1024 hidden columns (round-6 bug: 8 WGs/mb covered only 256). 8 waves =
// 4 ks x 2 jb; each wave: 16 j x 4 gates at K-quarter ks (wfrag 128 VGPRs).
// hbuf per-mb contiguous [mb][kb 128][b 16][8] -> A-frag loads are 1KB
// contiguous/instr. h publish: LDS gather -> wave0 single 64-lane x 16B
// contiguous store -> drain waits ONE instr. Barrier: flat per-mb counter,
// fan-in 32, leaders poll directly.
template <typename XG4>
__global__ __launch_bounds__(512, 2) void k_rec(
    const ushort_t* __restrict__ whhb, const XG4* __restrict__ xg4,
    const int* __restrict__ slenp, ushort_t* __restrict__ hbuf,
    float* __restrict__ out, int* __restrict__ cnt)
{
    const int tid = threadIdx.x;
    const int wave = tid >> 6, lane = tid & 63;
    const int ks = wave >> 1, jb = wave & 1;       // K-quarter, j-half
    const int wg = blockIdx.x;
    const int mb = wg >> 5;            // 0..3 batch block
    const int jw = wg & 31;            // 32-j slice (32 per mb -> full 1024)
    const int nn = lane & 15, q = lane >> 4;

    // B-fragments: 4 gates x 16 j rows at K-quarter ks, resident in VGPRs (128)
    short8 wfrag[4][8];
    {
        const short8* w8 = (const short8*)whhb;
        const int jr = jw * 32 + jb * 16 + nn;
#pragma unroll
        for (int g = 0; g < 4; g++) {
            const short8* wp = w8 + (size_t)(g * NHH + jr) * 128 + ks * 32;
#pragma unroll
            for (int u = 0; u < 8; u++) wfrag[g][u] = wp[u * 4 + q];
        }
    }
    const int eb = tid >> 5, ej = tid & 31;
    const int b_g = (mb << 4) + eb;    // elementwise thread's (batch, j)
    const int j_g = jw * 32 + ej;
    const int slen = slenp[b_g];
    const int blk_len = slenp[mb << 4]; // seq_len sorted desc -> block max

    int* cnt_mb = cnt + mb * 64;       // flat per-mb barrier counter (256B apart)

    __shared__ float red[4 * 32 * 84];     // [g][j 32][ks*20 + b 16], 43008 B
    __shared__ ushort_t htile[16 * 40];    // [b 16][j 32 + pad], 16B-aligned rows

    float c_st = 0.f, h_st = 0.f, hv_prev = 0.f;
    float4v xv = { 0.f, 0.f, 0.f, 0.f };
    if (0 < slen) xv = xg_load4(&xg4[(size_t)b_g * 1024 + j_g]);   // xg(0)

#pragma unroll 1
    for (int t = 0; t < blk_len; ++t) {
        // deferred out store for t-1 + xg(t+1) prefetch (off critical path)
        if (t > 0) out[((size_t)b_g * NT + (t - 1)) * 1024 + j_g] = hv_prev;
        float4v nxv = { 0.f, 0.f, 0.f, 0.f };
        if (t + 1 < slen) nxv = xg_load4(&xg4[((size_t)(t + 1) * 64 + b_g) * 1024 + j_g]);

        // A: 8 x (2x8B) agent loads; chunk = mb*2048 + (k/8)*16 + b15 -> each
        // instruction is a contiguous 1KB wave read
        const ull_t* hb8 = (const ull_t*)hbuf + (size_t)(t & 1) * 16384;
        ull_t raw[16];
#pragma unroll
        for (int u = 0; u < 8; u++) {
            size_t ch = (size_t)(mb * 2048 + (ks * 32 + u * 4 + q) * 16 + nn) * 2;
            raw[2 * u]     = __hip_atomic_load(&hb8[ch],     __ATOMIC_RELAXED, __HIP_MEMORY_SCOPE_AGENT);
            raw[2 * u + 1] = __hip_atomic_load(&hb8[ch + 1], __ATOMIC_RELAXED, __HIP_MEMORY_SCOPE_AGENT);
        }
        f32x4 acc[4];
#pragma unroll
        for (int g = 0; g < 4; g++) { f32x4 z = {0.f, 0.f, 0.f, 0.f}; acc[g] = z; }
#pragma unroll
        for (int u = 0; u < 8; u++) {
            ull2 p; p[0] = raw[2 * u]; p[1] = raw[2 * u + 1];
            short8 af = __builtin_bit_cast(short8, p);
#pragma unroll
            for (int g = 0; g < 4; g++)
                acc[g] = __builtin_amdgcn_mfma_f32_16x16x32_bf16(af, wfrag[g][u], acc[g], 0, 0, 0);
        }
        __syncthreads();   // red consumed last step
#pragma unroll
        for (int g = 0; g < 4; g++)
            *(f32x4*)&red[g * 2688 + (jb * 16 + nn) * 84 + ks * 20 + q * 4] = acc[g];
        __syncthreads();

        float hv = 0.f;
        if (t < slen) {
            float s[4];
#pragma unroll
            for (int g = 0; g < 4; g++) {
                const float* rp = &red[g * 2688 + ej * 84 + eb];
                s[g] = (rp[0] + rp[20]) + (rp[40] + rp[60]);
            }
            float ip = s[0] + xv[0];
            float fp = s[1] + xv[1];
            float gp = s[2] + xv[2];
            float op = s[3] + xv[3];
            float i_s = fsigmoid(ip), f_s = fsigmoid(fp);
            float g_t = ftanh(gp), o_s = fsigmoid(op);
            float cn = __builtin_fmaf(f_s, c_st, i_s * g_t);
            c_st = cn;
            h_st = o_s * ftanh(cn);
            hv = h_st;
        }
        hv_prev = hv;
        xv = nxv;
        htile[eb * 40 + ej] = f2bf(h_st);
        __syncthreads();                 // htile complete

        if (t + 1 < blk_len) {
            if (wave == 0) {
                // gather 16B (8 j x fixed b) and publish as ONE contiguous
                // 64-lane x 16B store; chunk = mb*2048 + jw*64 + lane
                // (jw in [0,32) -> exactly tiles the mb's 2048-chunk region)
                short8 hv8 = *(const short8*)&htile[(lane & 15) * 40 + (lane >> 4) * 8];
                ull2 pk = __builtin_bit_cast(ull2, hv8);
                ull_t* dst = (ull_t*)hbuf + (size_t)((t + 1) & 1) * 16384 +
                             (size_t)(mb * 2048 + jw * 64 + lane) * 2;
                __hip_atomic_store(&dst[0], pk[0], __ATOMIC_RELAXED, __HIP_MEMORY_SCOPE_AGENT);
                __hip_atomic_store(&dst[1], pk[1], __ATOMIC_RELAXED, __HIP_MEMORY_SCOPE_AGENT);
                asm volatile("s_waitcnt vmcnt(0)" ::: "memory");   // drain: 1 instr deep
                if (lane == 0) {
                    __hip_atomic_fetch_add(cnt_mb, 1, __ATOMIC_RELAXED, __HIP_MEMORY_SCOPE_AGENT);
                    const int target = (t + 1) << 5;   // 32 WGs per mb
                    while (__hip_atomic_load(cnt_mb, __ATOMIC_RELAXED, __HIP_MEMORY_SCOPE_AGENT) < target)
                        __builtin_amdgcn_s_sleep(1);
                }
            }
            __syncthreads();             // release all waves into step t+1
        }
    }
    // tail: last h output + zero padding past blk_len (overlapped across groups)
    out[((size_t)b_g * NT + (blk_len - 1)) * 1024 + j_g] = hv_prev;
    for (int t = blk_len; t < NT; ++t)
        out[((size_t)b_g * NT + t) * 1024 + j_g] = 0.f;
}

extern "C" void kernel_launch(void* const* d_in, const int* in_sizes, int n_in,
                              void* d_out, int out_size, void* d_ws, size_t ws_size,
                              hipStream_t stream)
{
    const float* feat = (const float*)d_in[0];
    const float* wih  = (const float*)d_in[1];
    const float* whh  = (const float*)d_in[2];
    const float* bih  = (const float*)d_in[3];
    const float* bhh  = (const float*)d_in[4];
    const int*   sl   = (const int*)d_in[5];
    float* out = (float*)d_out;
    char* ws = (char*)d_ws;

    size_t off = 0;
    auto take = [&](size_t bytes) -> size_t {
        size_t o = off; off += (bytes + 255) & ~(size_t)255; return o;
    };
    size_t o_featb = take((size_t)NB * NT * ND * 2);  // 64 MiB
    size_t o_wihb  = take((size_t)NG * ND * 2);       // 8 MiB
    size_t o_whhb  = take((size_t)NG * ND * 2);       // 8 MiB
    size_t o_hbuf  = take((size_t)2 * 65536 * 2);     // 256 KiB (2 bf16 h buffers)
    size_t o_cnt   = take(16384);                     // per-mb barrier counters
    size_t o_xg    = off;

    ushort_t* featb = (ushort_t*)(ws + o_featb);
    ushort_t* wihb  = (ushort_t*)(ws + o_wihb);
    ushort_t* whhb  = (ushort_t*)(ws + o_whhb);
    ushort_t* hbuf  = (ushort_t*)(ws + o_hbuf);
    int* cnt        = (int*)(ws + o_cnt);

    k_prep<<<2048, 256, 0, stream>>>(feat, wih, whh, featb, wihb, whhb, hbuf, cnt);

    size_t xg_elems = (size_t)NT * NB * NG;
    bool f32xg = (o_xg + xg_elems * 4) <= ws_size;    // prefer fp32 xg for accuracy
    if (f32xg) {
        float* xg = (float*)(ws + o_xg);
        k_gemm<float><<<8192, 256, 0, stream>>>(featb, wihb, bih, bhh, sl, xg);
        k_rec<float4v><<<128, 512, 0, stream>>>(whhb, (const float4v*)xg, sl, hbuf, out, cnt);
    } else {
        ushort_t* xg = (ushort_t*)(ws + o_xg);
        k_gemm<ushort_t><<<8192, 256, 0, stream>>>(featb, wihb, bih, bhh, sl, xg);
        k_rec<ushort4v><<<128, 512, 0, stream>>>(whhb, (const ushort4v*)xg, sl, hbuf, out, cnt);
    }
}